// Round 11
// baseline (618.450 us; speedup 1.0000x reference)
//
#include <hip/hip_runtime.h>
#include <stdint.h>

// LSTMBaseline: 2-layer, 1-step LSTM (zero init state) + decoder on MI355X.
//   h0 = lstm(x; W_ih0, b_ih0+b_hh0)   M=16384, K=512,  H=1024
//   h1 = lstm(h0; W_ih1, b_ih1+b_hh1)  K=1024
//   out = h1 @ W_dec^T + b_dec         N=512 (f32 out)
// f32 inputs -> bf16 prepass (x, gate-packed W_ih{0,1}, W_dec), then MFMA
// GEMMs. Round 11: NO-LDS direct-register GEMM. Both A and B fragments are
// loaded global->register (fragment pattern is 64B-line coalesced; A tile
// L1-resident across the wc-duplicate, B panel L2-resident across the 16
// by-blocks per XCD). No LDS, no barriers, no staging: the K-loop is 10 base
// pointers + immediate offsets + MFMA. R6's measured pipe balance had LDS
// (1435 cyc/block-tile) as the TOP pipe and the barrier as the coupler; six
// scheduling attempts showed any occupancy/coupling loss regresses -- this
// removes the pipe and the coupling instead.
// f-gate dead (c0=0), W_hh dead (h0=0).

typedef __attribute__((ext_vector_type(8))) __bf16 bf16x8;
typedef __attribute__((ext_vector_type(4))) float f32x4;

#define BM 128
#define BK 64

__device__ __forceinline__ unsigned short f2b(float f) {
    unsigned int x = __builtin_bit_cast(unsigned int, f);
    x = x + 0x7FFFu + ((x >> 16) & 1u);   // RNE
    return (unsigned short)(x >> 16);
}
__device__ __forceinline__ float sigf(float x) { return 1.0f / (1.0f + __expf(-x)); }
__device__ __forceinline__ float tanh_safe(float x) {
    float a = fabsf(x);
    float e = __expf(-2.0f * a);
    float t = (1.0f - e) / (1.0f + e);
    return x < 0.0f ? -t : t;
}

__device__ __forceinline__ void cvt8(const float* __restrict__ s,
                                     unsigned short* __restrict__ d) {
    f32x4 lo = *reinterpret_cast<const f32x4*>(s);
    f32x4 hi = *reinterpret_cast<const f32x4*>(s + 4);
    __attribute__((ext_vector_type(8))) unsigned short v;
    v[0] = f2b(lo[0]); v[1] = f2b(lo[1]); v[2] = f2b(lo[2]); v[3] = f2b(lo[3]);
    v[4] = f2b(hi[0]); v[5] = f2b(hi[1]); v[6] = f2b(hi[2]); v[7] = f2b(hi[3]);
    *reinterpret_cast<__attribute__((ext_vector_type(8))) unsigned short*>(d) = v;
}

// ---- pre-pass: f32 -> bf16 linear convert ---------------------------------
__global__ __launch_bounds__(256) void cvt_lin(const float* __restrict__ s,
                                               unsigned short* __restrict__ d,
                                               int n8) {
    int stride = gridDim.x * blockDim.x;
    for (int c = blockIdx.x * blockDim.x + threadIdx.x; c < n8; c += stride)
        cvt8(s + (size_t)c * 8, d + (size_t)c * 8);
}

// ---- pre-pass: gate-pack W (4H x K f32) -> (H/64 groups x 192 x K) bf16 ----
// Group G covers out-cols [G*64, G*64+64). Packed row r in group:
// r = wc*96 + (hsub*3 + gate)*16 + i; hcol = G*64 + wc*32 + hsub*16 + i;
// src row = {0,2H,3H}[gate] + hcol. Matches the GEMM's bv read order
// (wave wc, fragment n = hsub*3+gate). Same layout as R6.
__global__ __launch_bounds__(256) void pack_w(const float* __restrict__ W,
                                              unsigned short* __restrict__ d,
                                              int K8, int H, int n8) {
    int stride = gridDim.x * blockDim.x;
    for (int c = blockIdx.x * blockDim.x + threadIdx.x; c < n8; c += stride) {
        int dstRow = c / K8, kc = c - dstRow * K8;
        int G = dstRow / 192, r = dstRow - G * 192;
        int wc = r / 96, rr = r - wc * 96;
        int n = rr >> 4, i = rr & 15;
        int hsub = n / 3, gate = n - hsub * 3;
        int goff = (gate == 0) ? 0 : (gate + 1);   // {i,g,o} -> {0,2H,3H}
        int hcol = G * 64 + wc * 32 + hsub * 16 + i;
        cvt8(W + ((size_t)(goff * H + hcol) * K8 + kc) * 8, d + (size_t)c * 8);
    }
}

// ---- fused GEMM: 128-row tile, 4 waves (2Mx2N), all-register, no LDS ------
// Fragment loads: lane (l16 = row-in-16-group, hi8 = k-slot) reads 16B at
// row*K + (ks*4+hi8)*8 -- 16 rows x 64B lines, each line consumed by 4
// lanes (fully coalesced). All K-loop addresses are immediate offsets off
// 4 A-pointers + NFR B-pointers (K compile-time; max offset 1984B < 4KB).
// GATED=1: B 192 packed rows gate-major; acc[4][6]; activation -> bf16 h.
// GATED=0: 128x128; f32 out + bias.
template <int GATED, int K>
__global__ __launch_bounds__(256) void gemm_direct(
    const unsigned short* __restrict__ A,   // M x K bf16
    const unsigned short* __restrict__ Wp,  // packed/linear bf16, rows x K
    const float* __restrict__ b0,
    const float* __restrict__ b1,
    void* __restrict__ Ov,
    int M, int N, int NBX)
{
    constexpr int NFR   = GATED ? 6 : 4;     // col fragments per wave
    constexpr int BROWS = GATED ? 192 : 128; // B tile rows
    constexpr int WCS   = GATED ? 96 : 64;   // B rows per wave-col group
    constexpr int ONB   = GATED ? 64 : 128;  // out cols per block
    constexpr int NT    = K / BK;

    const int tid  = threadIdx.x;
    const int lane = tid & 63;
    const int w    = tid >> 6;
    const int wr   = w >> 1, wc = w & 1;
    const int l16  = lane & 15, hi8 = lane >> 4;

    // Bijective XCD swizzle (grids are multiples of 8): each XCD gets a
    // contiguous rid run -> A panels L2-shared across its 16 bx-blocks.
    const int cpx  = gridDim.x >> 3;
    const int orig = blockIdx.x;
    const int rid  = (orig & 7) * cpx + (orig >> 3);
    const int bx   = rid % NBX;
    const int by   = rid / NBX;
    const int row0 = by * BM;
    const int n0   = bx * ONB;

    // Base pointers (the ONLY address math; K-loop uses immediates).
    const unsigned short* aP[4];
#pragma unroll
    for (int m = 0; m < 4; ++m)
        aP[m] = A + (size_t)(row0 + wr * 64 + m * 16 + l16) * K + hi8 * 8;
    const unsigned short* bP[NFR];
#pragma unroll
    for (int n = 0; n < NFR; ++n) {
        int brow = (GATED ? bx * BROWS : n0) + wc * WCS + n * 16 + l16;
        bP[n] = Wp + (size_t)brow * K + hi8 * 8;
    }

    f32x4 acc[4][NFR];
#pragma unroll
    for (int m = 0; m < 4; ++m)
#pragma unroll
        for (int n = 0; n < NFR; ++n)
            acc[m][n] = (f32x4){0.f, 0.f, 0.f, 0.f};

#pragma unroll
    for (int t = 0; t < NT; ++t) {
        bf16x8 av[2][4], bv[2][NFR];
#pragma unroll
        for (int ks = 0; ks < 2; ++ks) {
#pragma unroll
            for (int m = 0; m < 4; ++m)
                av[ks][m] = *reinterpret_cast<const bf16x8*>(
                    aP[m] + t * 64 + ks * 32);
#pragma unroll
            for (int n = 0; n < NFR; ++n)
                bv[ks][n] = *reinterpret_cast<const bf16x8*>(
                    bP[n] + t * 64 + ks * 32);
        }
#pragma unroll
        for (int ks = 0; ks < 2; ++ks)
#pragma unroll
            for (int m = 0; m < 4; ++m)
#pragma unroll
                for (int n = 0; n < NFR; ++n)
                    acc[m][n] = __builtin_amdgcn_mfma_f32_16x16x32_bf16(
                        av[ks][m], bv[ks][n], acc[m][n], 0, 0, 0);
    }

    // ---- epilogue ----
    if constexpr (GATED) {
        unsigned short* O = (unsigned short*)Ov;
#pragma unroll
        for (int hsub = 0; hsub < 2; ++hsub) {
            const int hcol = n0 + wc * 32 + hsub * 16 + l16;
            const float bi = b0[hcol]         + b1[hcol];
            const float bg = b0[2 * N + hcol] + b1[2 * N + hcol];
            const float bo = b0[3 * N + hcol] + b1[3 * N + hcol];
#pragma unroll
            for (int m = 0; m < 4; ++m) {
                int rbase = row0 + wr * 64 + m * 16 + hi8 * 4;
#pragma unroll
                for (int q = 0; q < 4; ++q) {
                    float iv = sigf(acc[m][hsub * 3 + 0][q] + bi);
                    float gv = tanh_safe(acc[m][hsub * 3 + 1][q] + bg);
                    float ov = sigf(acc[m][hsub * 3 + 2][q] + bo);
                    float h  = ov * tanh_safe(iv * gv);
                    O[(size_t)(rbase + q) * N + hcol] = f2b(h);
                }
            }
        }
    } else {
        float* O = (float*)Ov;
#pragma unroll
        for (int n = 0; n < NFR; ++n) {
            int col = n0 + wc * WCS + n * 16 + l16;
            float bias = b0[col];
#pragma unroll
            for (int m = 0; m < 4; ++m) {
                int rbase = row0 + wr * 64 + m * 16 + hi8 * 4;
#pragma unroll
                for (int q = 0; q < 4; ++q)
                    O[(size_t)(rbase + q) * N + col] = acc[m][n][q] + bias;
            }
        }
    }
}

extern "C" void kernel_launch(void* const* d_in, const int* in_sizes, int n_in,
                              void* d_out, int out_size, void* d_ws, size_t ws_size,
                              hipStream_t stream) {
    constexpr int M = 16384, D = 512, H = 1024;

    const float* x    = (const float*)d_in[0];
    const float* Wih0 = (const float*)d_in[1];
    // d_in[2] = W_hh0: unused (h0 = 0)
    const float* bih0 = (const float*)d_in[3];
    const float* bhh0 = (const float*)d_in[4];
    const float* Wih1 = (const float*)d_in[5];
    // d_in[6] = W_hh1: unused
    const float* bih1 = (const float*)d_in[7];
    const float* bhh1 = (const float*)d_in[8];
    const float* Wdec = (const float*)d_in[9];
    const float* bdec = (const float*)d_in[10];

    const size_t szH = (size_t)M * H * 2;          // 33.5 MB
    const size_t sw0 = (size_t)3 * H * D * 2;      // 3.1 MB
    const size_t sw1 = (size_t)3 * H * H * 2;      // 6.3 MB

    unsigned short* h0 = (unsigned short*)d_ws;
    unsigned short* h1 = (unsigned short*)((char*)d_ws + szH);
    unsigned short* xb = h1;                       // alias: dead before L1 writes h1
    unsigned short* wp0   = (unsigned short*)((char*)d_ws + 2 * szH);
    unsigned short* wp1   = (unsigned short*)((char*)wp0 + sw0);
    unsigned short* wdecb = (unsigned short*)((char*)wp1 + sw1);

    cvt_lin<<<2048, 256, 0, stream>>>(x, xb, M * D / 8);
    pack_w <<<768,  256, 0, stream>>>(Wih0, wp0, D / 8, H, 3 * H * D / 8);
    pack_w <<<1536, 256, 0, stream>>>(Wih1, wp1, H / 8, H, 3 * H * H / 8);
    cvt_lin<<<256,  256, 0, stream>>>(Wdec, wdecb, D * H / 8);

    // layer 0: K=512; grid = (H/64) x (M/128) = 2048 blocks
    gemm_direct<1, 512><<<dim3((H / 64) * (M / BM)), 256, 0, stream>>>(
        xb, wp0, bih0, bhh0, h0, M, H, H / 64);
    // layer 1: K=1024
    gemm_direct<1, 1024><<<dim3((H / 64) * (M / BM)), 256, 0, stream>>>(
        h0, wp1, bih1, bhh1, h1, M, H, H / 64);
    // decoder: N=512; grid = (D/128) x (M/128) = 512 blocks
    gemm_direct<0, 1024><<<dim3((D / 128) * (M / BM)), 256, 0, stream>>>(
        h1, wdecb, bdec, nullptr, (float*)d_out, M, D, D / 128);
}

// Round 12
// 210.570 us; speedup vs baseline: 2.9370x; 2.9370x over previous
//
#include <hip/hip_runtime.h>
#include <stdint.h>

// LSTMBaseline: 2-layer, 1-step LSTM (zero init state) + decoder on MI355X.
//   h0 = lstm(x; W_ih0, b_ih0+b_hh0)   M=16384, K=512,  H=1024
//   h1 = lstm(h0; W_ih1, b_ih1+b_hh1)  K=1024
//   out = h1 @ W_dec^T + b_dec         N=512 (f32 out)
// Round 12 = R6 champion (215.6us) restored verbatim + the 4 prepass
// kernels fused into one launch. R6 GEMM: 2-barrier K-loop, gated 128x64-out
// tiles (B=192 gate-major rows, acc[4][6], 4.8 MFMA/KB staged), decoder
// 128x128, global_load_lds w16 with XOR-swizzled source + swizzled ds_read,
// bijective XCD block swizzle. Structural alternatives R4/R5/R7/R8/R9/R11
// all regressed (occupancy loss or load-MFMA coupling); this structure is
// ~88% of its measured ceiling. f-gate dead (c0=0), W_hh dead (h0=0).

typedef __attribute__((ext_vector_type(8))) __bf16 bf16x8;
typedef __attribute__((ext_vector_type(4))) float f32x4;

#define BM 128
#define BK 64

__device__ __forceinline__ unsigned short f2b(float f) {
    unsigned int x = __builtin_bit_cast(unsigned int, f);
    x = x + 0x7FFFu + ((x >> 16) & 1u);   // RNE
    return (unsigned short)(x >> 16);
}
__device__ __forceinline__ float sigf(float x) { return 1.0f / (1.0f + __expf(-x)); }
__device__ __forceinline__ float tanh_safe(float x) {
    float a = fabsf(x);
    float e = __expf(-2.0f * a);
    float t = (1.0f - e) / (1.0f + e);
    return x < 0.0f ? -t : t;
}

__device__ __forceinline__ void cvt8(const float* __restrict__ s,
                                     unsigned short* __restrict__ d) {
    f32x4 lo = *reinterpret_cast<const f32x4*>(s);
    f32x4 hi = *reinterpret_cast<const f32x4*>(s + 4);
    __attribute__((ext_vector_type(8))) unsigned short v;
    v[0] = f2b(lo[0]); v[1] = f2b(lo[1]); v[2] = f2b(lo[2]); v[3] = f2b(lo[3]);
    v[4] = f2b(hi[0]); v[5] = f2b(hi[1]); v[6] = f2b(hi[2]); v[7] = f2b(hi[3]);
    *reinterpret_cast<__attribute__((ext_vector_type(8))) unsigned short*>(d) = v;
}

__device__ __forceinline__ void gload16(const unsigned short* g, unsigned short* l) {
    __builtin_amdgcn_global_load_lds(
        (const __attribute__((address_space(1))) void*)g,
        (__attribute__((address_space(3))) void*)l,
        16, 0, 0);
}

// ---- gate-pack one 8-elem chunk of W (4H x K f32) into the GEMM B order ---
// (H/64 groups x 192 x K) bf16. Group G covers out-cols [G*64, G*64+64).
// Packed row r in group: r = wc*96 + (hsub*3 + gate)*16 + i;
// hcol = G*64 + wc*32 + hsub*16 + i; src row = {0,2H,3H}[gate] + hcol.
__device__ __forceinline__ void pack_one(const float* __restrict__ W,
                                         unsigned short* __restrict__ d,
                                         int K8, int H, int c) {
    int dstRow = c / K8, kc = c - dstRow * K8;
    int G = dstRow / 192, r = dstRow - G * 192;
    int wc = r / 96, rr = r - wc * 96;
    int n = rr >> 4, i = rr & 15;
    int hsub = n / 3, gate = n - hsub * 3;
    int goff = (gate == 0) ? 0 : (gate + 1);   // {i,g,o} -> {0,2H,3H}
    int hcol = G * 64 + wc * 32 + hsub * 16 + i;
    cvt8(W + ((size_t)(goff * H + hcol) * K8 + kc) * 8, d + (size_t)c * 8);
}

// ---- fused pre-pass: one launch does all 4 conversions ---------------------
// blocks [0,2048): x f32->bf16 (2 chunks/thread); [2048,2816): pack W_ih0;
// [2816,4352): pack W_ih1; [4352,4608): W_dec f32->bf16.
__global__ __launch_bounds__(256) void prepass(
    const float* __restrict__ x,   const float* __restrict__ W0,
    const float* __restrict__ W1,  const float* __restrict__ Wd,
    unsigned short* __restrict__ xb,  unsigned short* __restrict__ wp0,
    unsigned short* __restrict__ wp1, unsigned short* __restrict__ wdecb)
{
    const int tid = threadIdx.x;
    const int b   = blockIdx.x;
    if (b < 2048) {                       // x: 1,048,576 chunks
        int c = b * 256 + tid;
        cvt8(x + (size_t)c * 8, xb + (size_t)c * 8);
        c += 2048 * 256;
        cvt8(x + (size_t)c * 8, xb + (size_t)c * 8);
    } else if (b < 2816) {                // W_ih0: 196,608 chunks, K8=64
        pack_one(W0, wp0, 64, 1024, (b - 2048) * 256 + tid);
    } else if (b < 4352) {                // W_ih1: 393,216 chunks, K8=128
        pack_one(W1, wp1, 128, 1024, (b - 2816) * 256 + tid);
    } else {                              // W_dec: 65,536 chunks
        int c = (b - 4352) * 256 + tid;
        cvt8(Wd + (size_t)c * 8, wdecb + (size_t)c * 8);
    }
}

// ---- fused GEMM: 128-row tile, 4 waves (2Mx2N), 2-barrier K-loop ----------
// GATED=1: B 192 rows (packed gate-major per 64 out-cols); wave acc[4][6]
//   (n = hsub*3+gate); per-lane activation epilogue -> bf16 h (2 cols/lane).
// GATED=0: m97-style 128x128; B rows = out cols linear; f32 out + bias.
template <int GATED>
__global__ __launch_bounds__(256, 3) void gemm_fused(
    const unsigned short* __restrict__ A,   // M x K bf16
    const unsigned short* __restrict__ Wp,  // packed/linear bf16, rows x K
    const float* __restrict__ b0,
    const float* __restrict__ b1,
    void* __restrict__ Ov,
    int M, int K, int N, int NBX)
{
    constexpr int NFR   = GATED ? 6 : 4;     // col fragments per wave
    constexpr int BROWS = GATED ? 192 : 128; // B tile rows
    constexpr int WCS   = GATED ? 96 : 64;   // B rows per wave-col group
    constexpr int ONB   = GATED ? 64 : 128;  // out cols per block
    constexpr int NBCH  = BROWS / 32;        // B gloads per thread (6 / 4)

    __shared__ __align__(16) unsigned short sA[BM * BK];
    __shared__ __align__(16) unsigned short sB[BROWS * BK];

    const int tid  = threadIdx.x;
    const int lane = tid & 63;
    const int w    = tid >> 6;
    const int wr   = w >> 1, wc = w & 1;
    const int l16  = lane & 15, hi8 = lane >> 4;

    // Bijective XCD swizzle (grids are multiples of 8).
    const int cpx  = gridDim.x >> 3;
    const int orig = blockIdx.x;
    const int rid  = (orig & 7) * cpx + (orig >> 3);
    const int bx   = rid % NBX;
    const int by   = rid / NBX;
    const int row0 = by * BM;
    const int n0   = bx * ONB;

    // Staging: chunk i covers row (tid>>3)+i*32, k-slot sl=tid&7. Global
    // source pre-swizzled (ls = sl^(row&7), row&7==r0&7 since stride 32);
    // LDS dest linear (tid*8+i*2048) per global_load_lds rules.
    const int r0 = tid >> 3, sl = tid & 7;
    const int ls = sl ^ (r0 & 7);
    const unsigned int strd = 32u * (unsigned)K;
    unsigned int offA = (unsigned)(row0 + r0) * (unsigned)K + ls * 8;
    unsigned int offB = (unsigned)((GATED ? bx * BROWS : n0) + r0)
                        * (unsigned)K + ls * 8;

    f32x4 acc[4][NFR];
#pragma unroll
    for (int m = 0; m < 4; ++m)
#pragma unroll
        for (int n = 0; n < NFR; ++n)
            acc[m][n] = (f32x4){0.f, 0.f, 0.f, 0.f};

    for (int k0 = 0; k0 < K; k0 += BK) {
#pragma unroll
        for (int i = 0; i < 4; ++i)
            gload16(A + offA + i * strd + k0, sA + tid * 8 + i * 2048);
#pragma unroll
        for (int i = 0; i < NBCH; ++i)
            gload16(Wp + offB + i * strd + k0, sB + tid * 8 + i * 2048);
        __syncthreads();   // drains vmcnt: staged tile visible

#pragma unroll
        for (int ks = 0; ks < 2; ++ks) {
            bf16x8 av[4], bv[NFR];
#pragma unroll
            for (int m = 0; m < 4; ++m) {
                int row = wr * 64 + m * 16 + l16;
                int ps = (ks * 4 + hi8) ^ (row & 7);
                av[m] = *reinterpret_cast<const bf16x8*>(sA + row * BK + ps * 8);
            }
#pragma unroll
            for (int n = 0; n < NFR; ++n) {
                int row = wc * WCS + n * 16 + l16;
                int ps = (ks * 4 + hi8) ^ (row & 7);
                bv[n] = *reinterpret_cast<const bf16x8*>(sB + row * BK + ps * 8);
            }
#pragma unroll
            for (int m = 0; m < 4; ++m)
#pragma unroll
                for (int n = 0; n < NFR; ++n)
                    acc[m][n] = __builtin_amdgcn_mfma_f32_16x16x32_bf16(
                        av[m], bv[n], acc[m][n], 0, 0, 0);
        }
        __syncthreads();   // protect LDS before next stage
    }

    // ---- epilogue ----
    if constexpr (GATED) {
        unsigned short* O = (unsigned short*)Ov;
#pragma unroll
        for (int hsub = 0; hsub < 2; ++hsub) {
            const int hcol = n0 + wc * 32 + hsub * 16 + l16;
            const float bi = b0[hcol]         + b1[hcol];
            const float bg = b0[2 * N + hcol] + b1[2 * N + hcol];
            const float bo = b0[3 * N + hcol] + b1[3 * N + hcol];
#pragma unroll
            for (int m = 0; m < 4; ++m) {
                int rbase = row0 + wr * 64 + m * 16 + hi8 * 4;
#pragma unroll
                for (int q = 0; q < 4; ++q) {
                    float iv = sigf(acc[m][hsub * 3 + 0][q] + bi);
                    float gv = tanh_safe(acc[m][hsub * 3 + 1][q] + bg);
                    float ov = sigf(acc[m][hsub * 3 + 2][q] + bo);
                    float h  = ov * tanh_safe(iv * gv);
                    O[(size_t)(rbase + q) * N + hcol] = f2b(h);
                }
            }
        }
    } else {
        float* O = (float*)Ov;
#pragma unroll
        for (int n = 0; n < NFR; ++n) {
            int col = n0 + wc * WCS + n * 16 + l16;
            float bias = b0[col];
#pragma unroll
            for (int m = 0; m < 4; ++m) {
                int rbase = row0 + wr * 64 + m * 16 + hi8 * 4;
#pragma unroll
                for (int q = 0; q < 4; ++q)
                    O[(size_t)(rbase + q) * N + col] = acc[m][n][q] + bias;
            }
        }
    }
}

extern "C" void kernel_launch(void* const* d_in, const int* in_sizes, int n_in,
                              void* d_out, int out_size, void* d_ws, size_t ws_size,
                              hipStream_t stream) {
    constexpr int M = 16384, D = 512, H = 1024;

    const float* x    = (const float*)d_in[0];
    const float* Wih0 = (const float*)d_in[1];
    // d_in[2] = W_hh0: unused (h0 = 0)
    const float* bih0 = (const float*)d_in[3];
    const float* bhh0 = (const float*)d_in[4];
    const float* Wih1 = (const float*)d_in[5];
    // d_in[6] = W_hh1: unused
    const float* bih1 = (const float*)d_in[7];
    const float* bhh1 = (const float*)d_in[8];
    const float* Wdec = (const float*)d_in[9];
    const float* bdec = (const float*)d_in[10];

    const size_t szH = (size_t)M * H * 2;          // 33.5 MB
    const size_t sw0 = (size_t)3 * H * D * 2;      // 3.1 MB
    const size_t sw1 = (size_t)3 * H * H * 2;      // 6.3 MB

    unsigned short* h0 = (unsigned short*)d_ws;
    unsigned short* h1 = (unsigned short*)((char*)d_ws + szH);
    unsigned short* xb = h1;                       // alias: dead before L1 writes h1
    unsigned short* wp0   = (unsigned short*)((char*)d_ws + 2 * szH);
    unsigned short* wp1   = (unsigned short*)((char*)wp0 + sw0);
    unsigned short* wdecb = (unsigned short*)((char*)wp1 + sw1);

    // Fused pre-pass: x->bf16, gate-pack W_ih0/W_ih1, W_dec->bf16 (1 launch).
    prepass<<<4608, 256, 0, stream>>>(x, Wih0, Wih1, Wdec, xb, wp0, wp1, wdecb);

    // layer 0: K=512; grid = (H/64) x (M/128) = 16 x 128 = 2048 blocks
    gemm_fused<1><<<dim3((H / 64) * (M / BM)), 256, 0, stream>>>(
        xb, wp0, bih0, bhh0, h0, M, D, H, H / 64);
    // layer 1: K=1024
    gemm_fused<1><<<dim3((H / 64) * (M / BM)), 256, 0, stream>>>(
        h0, wp1, bih1, bhh1, h1, M, H, H, H / 64);
    // decoder: N=512; grid = (D/128) x (M/128) = 4 x 128 = 512 blocks
    gemm_fused<0><<<dim3((D / 128) * (M / BM)), 256, 0, stream>>>(
        h1, wdecb, bdec, nullptr, (float*)d_out, M, H, D, D / 128);
}